// Round 16
// baseline (238.740 us; speedup 1.0000x reference)
//
#include <hip/hip_runtime.h>
#include <stdint.h>

#define TT  4096   // tokens = B*S
#define HD  1024   // hidden
#define NE  8      // experts
#define ID  1024   // expert intermediate
#define SID 2816   // shared intermediate

typedef short s16x8 __attribute__((ext_vector_type(8)));
typedef float f32x4 __attribute__((ext_vector_type(4)));
typedef float f32x4v __attribute__((ext_vector_type(4)));
typedef unsigned short u16x4 __attribute__((ext_vector_type(4)));

__device__ __forceinline__ ushort f2bf(float f) {
  uint32_t u = __float_as_uint(f);
  u += 0x7FFFu + ((u >> 16) & 1u);   // RNE
  return (ushort)(u >> 16);
}

__device__ __forceinline__ void gll16(const ushort* g, ushort* l) {
  __builtin_amdgcn_global_load_lds(
      (const __attribute__((address_space(1))) void*)g,
      (__attribute__((address_space(3))) void*)l, 16, 0, 0);
}

// ---------------- prep: router ∥ gu-path weight cvt (one launch) -----------
#define RTR_BLKS 256
#define CVT_BLKS 2048

struct PrepArgs {
  const float* src[4];
  ushort* dst[4];
  int n[4];
  const float* X;
  const float* gw;
  const float* sgw;
  ushort* Xb;
  int* topki;
  float* topkw;
  float* sgate;
};

__global__ __launch_bounds__(256) void prep_k(PrepArgs a) {
  __shared__ float gwL[(NE + 1) * HD];   // router blocks only (36KB)
  const int id = blockIdx.x;
  const int tid = threadIdx.x;

  if (id < RTR_BLKS) {
    // ---- router (pure; also emits Xb = bf16(X)) ----
    #pragma unroll
    for (int i = 0; i < NE * HD / 1024; i++) {
      int idx = i * 1024 + tid * 4;
      *(f32x4*)&gwL[idx] = *(const f32x4*)&a.gw[idx];
    }
    {
      int idx = tid * 4;
      if (idx < HD) *(f32x4*)&gwL[NE * HD + idx] = *(const f32x4*)&a.sgw[idx];
    }
    __syncthreads();

    const int wave = tid >> 6, lane = tid & 63;
    #pragma unroll
    for (int tt = 0; tt < 4; tt++) {
      const int t = id * 16 + wave * 4 + tt;
      const float* x = a.X + (size_t)t * HD;
      float acc[NE + 1];
      #pragma unroll
      for (int e = 0; e <= NE; e++) acc[e] = 0.f;
      #pragma unroll
      for (int p = 0; p < HD / 256; p++) {
        const int k = p * 256 + lane * 4;
        f32x4 xv = *(const f32x4*)&x[k];
        u16x4 xb;
        xb.x = f2bf(xv.x); xb.y = f2bf(xv.y); xb.z = f2bf(xv.z); xb.w = f2bf(xv.w);
        *(u16x4*)&a.Xb[(size_t)t * HD + k] = xb;
        #pragma unroll
        for (int e = 0; e < NE; e++) {
          f32x4 g = *(const f32x4*)&gwL[e * HD + k];
          acc[e] += xv.x * g.x + xv.y * g.y + xv.z * g.z + xv.w * g.w;
        }
        f32x4 s = *(const f32x4*)&gwL[NE * HD + k];
        acc[NE] += xv.x * s.x + xv.y * s.y + xv.z * s.z + xv.w * s.w;
      }
      #pragma unroll
      for (int off = 32; off > 0; off >>= 1)
        #pragma unroll
        for (int e = 0; e <= NE; e++)
          acc[e] += __shfl_xor(acc[e], off, 64);
      if (lane == 0) {
        float m = acc[0];
        #pragma unroll
        for (int e = 1; e < NE; e++) m = fmaxf(m, acc[e]);
        float p[NE];
        #pragma unroll
        for (int e = 0; e < NE; e++) p[e] = __expf(acc[e] - m);
        int i1 = 0;
        #pragma unroll
        for (int e = 1; e < NE; e++) if (p[e] > p[i1]) i1 = e;
        int i2 = (i1 == 0) ? 1 : 0;
        #pragma unroll
        for (int e = 0; e < NE; e++) if (e != i1 && p[e] > p[i2]) i2 = e;
        float inv = 1.f / (p[i1] + p[i2]);
        a.topki[2 * t] = i1; a.topki[2 * t + 1] = i2;
        a.topkw[2 * t] = p[i1] * inv; a.topkw[2 * t + 1] = p[i2] * inv;
        a.sgate[t] = 1.f / (1.f + __expf(-acc[NE]));
      }
    }
  } else {
    // ---- gu-path weight cvt (wg, wu, swg, swu), coalesced grid-stride ----
    const int cid = id - RTR_BLKS;
    #pragma unroll
    for (int t = 0; t < 4; t++) {
      const float* s = a.src[t];
      ushort* d = a.dst[t];
      const int n = a.n[t];
      for (int i = (cid * 256 + tid) * 4; i < n; i += CVT_BLKS * 1024) {
        f32x4v v = *(const f32x4v*)(s + i);
        u16x4 o;
        o.x = f2bf(v.x); o.y = f2bf(v.y); o.z = f2bf(v.z); o.w = f2bf(v.w);
        *(u16x4*)(d + i) = o;
      }
    }
  }
}

// ---------------- binning: ballot-based, zero atomics ----------------------
__global__ __launch_bounds__(1024) void binning_k(
    const int* __restrict__ topki, const float* __restrict__ topkw,
    int* __restrict__ cnt, int* __restrict__ offs,
    int* __restrict__ tokmap, float* __restrict__ wmap) {
  __shared__ int wc[16][NE];
  __shared__ int wbase[16][NE];
  const int tid = threadIdx.x;
  const int wave = tid >> 6, lane = tid & 63;
  const uint64_t ltmask = ((uint64_t)1 << lane) - 1;

  int wcnt[NE];
  #pragma unroll
  for (int e = 0; e < NE; e++) wcnt[e] = 0;
  int mye[8], myoff[8];
  #pragma unroll
  for (int it = 0; it < 8; it++) {
    int s = wave * 512 + it * 64 + lane;
    int e = topki[s];
    mye[it] = e;
    myoff[it] = 0;
    #pragma unroll
    for (int ee = 0; ee < NE; ee++) {
      uint64_t m = __ballot(e == ee);
      if (e == ee) myoff[it] = wcnt[ee] + __popcll(m & ltmask);
      wcnt[ee] += __popcll(m);
    }
  }
  if (lane == 0) {
    #pragma unroll
    for (int e = 0; e < NE; e++) wc[wave][e] = wcnt[e];
  }
  __syncthreads();
  if (tid == 0) {
    int o = 0;
    for (int e = 0; e < NE; e++) {
      offs[e] = o;
      int tot = 0;
      for (int w = 0; w < 16; w++) { wbase[w][e] = o + tot; tot += wc[w][e]; }
      cnt[e] = tot;
      o += tot;
    }
  }
  __syncthreads();
  #pragma unroll
  for (int it = 0; it < 8; it++) {
    int s = wave * 512 + it * 64 + lane;
    int e = mye[it];
    int pos = wbase[wave][e] + myoff[it];
    tokmap[pos] = s >> 1;
    wmap[pos] = topkw[s];
  }
}

// ---------------- GEMM cores (128-tile, 2-buf, swizzled, LDS passed in) ----
// LDS rows 64B (32 bf16). Write side pre-swizzles GLOBAL 16B chunk
// ((l&3)^((l>>3)&3)); LDS dest linear (global_load_lds rule); read side
// applies same involution -> 0 bank conflicts (verified R3/R9/R10).
constexpr int BM = 128, BN = 128, BK = 32;

template <bool GATHER>
__device__ __forceinline__ void gu_core(
    const ushort* __restrict__ A, const ushort* __restrict__ Wg,
    const ushort* __restrict__ Wu, ushort* __restrict__ Hout,
    const int* __restrict__ tokmap, int cnt, int seg,
    int mb, int nb, int N, int K, ushort* lds) {
  const int m0 = mb * BM;
  if (m0 >= cnt) return;
  const int n0 = nb * BN;

  ushort* lA  = lds;           // 2 x 4096
  ushort* lBg = lds + 8192;    // 2 x 4096
  ushort* lBu = lds + 16384;   // 2 x 4096

  const int tid = threadIdx.x;
  const int wave = tid >> 6, lane = tid & 63;
  const int wm = (wave >> 1) * 64, wn = (wave & 1) * 64;

  const int ar0 = wave * 32 + (lane >> 2);
  const int ar1 = ar0 + 16;
  const int kc = ((lane & 3) ^ ((lane >> 3) & 3)) * 8;

  const ushort *a0p, *a1p;
  if (GATHER) {
    int m_ = m0 + ar0;
    int tk0 = (m_ < cnt) ? tokmap[seg + m_] : 0;
    m_ = m0 + ar1;
    int tk1 = (m_ < cnt) ? tokmap[seg + m_] : 0;
    a0p = A + (size_t)tk0 * K + kc;
    a1p = A + (size_t)tk1 * K + kc;
  } else {
    a0p = A + (size_t)(m0 + ar0) * K + kc;
    a1p = A + (size_t)(m0 + ar1) * K + kc;
  }
  const ushort* bg0 = Wg + (size_t)(n0 + ar0) * K + kc;
  const ushort* bg1 = Wg + (size_t)(n0 + ar1) * K + kc;
  const ushort* bu0 = Wu + (size_t)(n0 + ar0) * K + kc;
  const ushort* bu1 = Wu + (size_t)(n0 + ar1) * K + kc;

  f32x4 accG[4][4], accU[4][4];
  #pragma unroll
  for (int i = 0; i < 4; i++)
    #pragma unroll
    for (int j = 0; j < 4; j++) {
      accG[i][j] = f32x4{0.f, 0.f, 0.f, 0.f};
      accU[i][j] = f32x4{0.f, 0.f, 0.f, 0.f};
    }

  const int lr = lane & 15;
  const int lk = (((lane >> 4) ^ ((lr >> 1) & 3))) * 8;
  const int w32 = wave * 32;

  auto stage = [&](int b, int k0) {
    gll16(a0p + k0, &lA[b * 4096 + w32 * BK]);
    gll16(a1p + k0, &lA[b * 4096 + (w32 + 16) * BK]);
    gll16(bg0 + k0, &lBg[b * 4096 + w32 * BK]);
    gll16(bg1 + k0, &lBg[b * 4096 + (w32 + 16) * BK]);
    gll16(bu0 + k0, &lBu[b * 4096 + w32 * BK]);
    gll16(bu1 + k0, &lBu[b * 4096 + (w32 + 16) * BK]);
  };

  const int nt = K / BK;
  stage(0, 0);
  for (int t = 0; t < nt; t++) {
    const int cur = t & 1;
    if (t + 1 < nt) {
      stage(cur ^ 1, (t + 1) * BK);
      asm volatile("s_waitcnt vmcnt(6)" ::: "memory");
    } else {
      asm volatile("s_waitcnt vmcnt(0)" ::: "memory");
    }
    __builtin_amdgcn_s_barrier();

    s16x8 af[4], bgf[4], buf_[4];
    #pragma unroll
    for (int i = 0; i < 4; i++) {
      af[i]   = *(const s16x8*)&lA [cur * 4096 + (wm + i * 16 + lr) * BK + lk];
      bgf[i]  = *(const s16x8*)&lBg[cur * 4096 + (wn + i * 16 + lr) * BK + lk];
      buf_[i] = *(const s16x8*)&lBu[cur * 4096 + (wn + i * 16 + lr) * BK + lk];
    }
    #pragma unroll
    for (int i = 0; i < 4; i++)
      #pragma unroll
      for (int j = 0; j < 4; j++) {
        accG[i][j] = __builtin_amdgcn_mfma_f32_16x16x32_bf16(af[i], bgf[j], accG[i][j], 0, 0, 0);
        accU[i][j] = __builtin_amdgcn_mfma_f32_16x16x32_bf16(af[i], buf_[j], accU[i][j], 0, 0, 0);
      }
    __builtin_amdgcn_s_barrier();
  }

  const int lrr = (lane >> 4) * 4;
  #pragma unroll
  for (int i = 0; i < 4; i++) {
    #pragma unroll
    for (int r = 0; r < 4; r++) {
      int m = wm + i * 16 + lrr + r;
      if (m0 + m < cnt) {
        size_t row = (size_t)(seg + m0 + m) * N;
        #pragma unroll
        for (int j = 0; j < 4; j++) {
          int c = n0 + wn + j * 16 + lr;
          float g = accG[i][j][r];
          float u = accU[i][j][r];
          float s = g / (1.f + __expf(-g));   // silu
          Hout[row + c] = f2bf(s * u);
        }
      }
    }
  }
}

// routed down-proj 128x128 core: atomicAdd(w * val) direct to out
__device__ __forceinline__ void dn_r_core(
    const ushort* __restrict__ A, const ushort* __restrict__ W,
    float* __restrict__ out, const int* __restrict__ tokmap,
    const float* __restrict__ wmap, int cnt, int seg,
    int mb, int nb, int N, int K, ushort* lds) {
  const int m0 = mb * BM;
  if (m0 >= cnt) return;
  const int n0 = nb * BN;

  ushort* lA = lds;          // 2 x 4096
  ushort* lB = lds + 8192;   // 2 x 4096

  const int tid = threadIdx.x;
  const int wave = tid >> 6, lane = tid & 63;
  const int wm = (wave >> 1) * 64, wn = (wave & 1) * 64;

  const int ar0 = wave * 32 + (lane >> 2);
  const int ar1 = ar0 + 16;
  const int kc = ((lane & 3) ^ ((lane >> 3) & 3)) * 8;

  int r0 = m0 + ar0; if (r0 > cnt - 1) r0 = cnt - 1;
  int r1 = m0 + ar1; if (r1 > cnt - 1) r1 = cnt - 1;
  const ushort* a0p = A + (size_t)(seg + r0) * K + kc;
  const ushort* a1p = A + (size_t)(seg + r1) * K + kc;
  const ushort* b0 = W + (size_t)(n0 + ar0) * K + kc;
  const ushort* b1 = W + (size_t)(n0 + ar1) * K + kc;

  f32x4 acc[4][4];
  #pragma unroll
  for (int i = 0; i < 4; i++)
    #pragma unroll
    for (int j = 0; j < 4; j++) acc[i][j] = f32x4{0.f, 0.f, 0.f, 0.f};

  const int lr = lane & 15;
  const int lk = (((lane >> 4) ^ ((lr >> 1) & 3))) * 8;
  const int w32 = wave * 32;

  auto stage = [&](int b, int k0) {
    gll16(a0p + k0, &lA[b * 4096 + w32 * BK]);
    gll16(a1p + k0, &lA[b * 4096 + (w32 + 16) * BK]);
    gll16(b0 + k0, &lB[b * 4096 + w32 * BK]);
    gll16(b1 + k0, &lB[b * 4096 + (w32 + 16) * BK]);
  };

  const int nt = K / BK;
  stage(0, 0);
  for (int t = 0; t < nt; t++) {
    const int cur = t & 1;
    if (t + 1 < nt) {
      stage(cur ^ 1, (t + 1) * BK);
      asm volatile("s_waitcnt vmcnt(4)" ::: "memory");
    } else {
      asm volatile("s_waitcnt vmcnt(0)" ::: "memory");
    }
    __builtin_amdgcn_s_barrier();

    s16x8 af[4], bf[4];
    #pragma unroll
    for (int i = 0; i < 4; i++) {
      af[i] = *(const s16x8*)&lA[cur * 4096 + (wm + i * 16 + lr) * BK + lk];
      bf[i] = *(const s16x8*)&lB[cur * 4096 + (wn + i * 16 + lr) * BK + lk];
    }
    #pragma unroll
    for (int i = 0; i < 4; i++)
      #pragma unroll
      for (int j = 0; j < 4; j++)
        acc[i][j] = __builtin_amdgcn_mfma_f32_16x16x32_bf16(af[i], bf[j], acc[i][j], 0, 0, 0);
    __builtin_amdgcn_s_barrier();
  }

  const int lrr = (lane >> 4) * 4;
  #pragma unroll
  for (int i = 0; i < 4; i++) {
    #pragma unroll
    for (int r = 0; r < 4; r++) {
      int m = wm + i * 16 + lrr + r;
      if (m0 + m < cnt) {
        int slot = seg + m0 + m;
        int t = tokmap[slot];
        float wv = wmap[slot];
        size_t row = (size_t)t * N;
        #pragma unroll
        for (int j = 0; j < 4; j++) {
          int c = n0 + wn + j * 16 + lr;
          atomicAdd(&out[row + c], wv * acc[i][j][r]);
        }
      }
    }
  }
}

// shared down-proj 128x64 core: atomicAdd(sgate * val) to out
__device__ __forceinline__ void dn_s_core(
    const ushort* __restrict__ A, const ushort* __restrict__ W,
    float* __restrict__ out, const float* __restrict__ sgate,
    int mb, int nb, int N, int K, ushort* lds) {
  const int m0 = mb * 128, n0 = nb * 64;

  ushort* lA = lds;          // 2 x 4096
  ushort* lB = lds + 8192;   // 2 x 2048

  const int tid = threadIdx.x;
  const int wave = tid >> 6, lane = tid & 63;
  const int wm = (wave >> 1) * 64, wn = (wave & 1) * 32;

  const int ar0 = wave * 32 + (lane >> 2);
  const int ar1 = ar0 + 16;
  const int br  = wave * 16 + (lane >> 2);
  const int kc = ((lane & 3) ^ ((lane >> 3) & 3)) * 8;

  const ushort* a0p = A + (size_t)(m0 + ar0) * K + kc;
  const ushort* a1p = A + (size_t)(m0 + ar1) * K + kc;
  const ushort* bp  = W + (size_t)(n0 + br) * K + kc;

  f32x4 acc[4][2];
  #pragma unroll
  for (int i = 0; i < 4; i++)
    #pragma unroll
    for (int j = 0; j < 2; j++) acc[i][j] = f32x4{0.f, 0.f, 0.f, 0.f};

  const int lr = lane & 15;
  const int lk = (((lane >> 4) ^ ((lr >> 1) & 3))) * 8;
  const int w32 = wave * 32;

  auto stage = [&](int b, int k0) {
    gll16(a0p + k0, &lA[b * 4096 + w32 * 32]);
    gll16(a1p + k0, &lA[b * 4096 + (w32 + 16) * 32]);
    gll16(bp + k0, &lB[b * 2048 + wave * 512]);
  };

  const int nt = K / 32;
  stage(0, 0);
  for (int t = 0; t < nt; t++) {
    const int cur = t & 1;
    if (t + 1 < nt) {
      stage(cur ^ 1, (t + 1) * 32);
      asm volatile("s_waitcnt vmcnt(3)" ::: "memory");
    } else {
      asm volatile("s_waitcnt vmcnt(0)" ::: "memory");
    }
    __builtin_amdgcn_s_barrier();

    s16x8 af[4], bf[2];
    #pragma unroll
    for (int i = 0; i < 4; i++)
      af[i] = *(const s16x8*)&lA[cur * 4096 + (wm + i * 16 + lr) * 32 + lk];
    #pragma unroll
    for (int j = 0; j < 2; j++)
      bf[j] = *(const s16x8*)&lB[cur * 2048 + (wn + j * 16 + lr) * 32 + lk];
    #pragma unroll
    for (int i = 0; i < 4; i++)
      #pragma unroll
      for (int j = 0; j < 2; j++)
        acc[i][j] = __builtin_amdgcn_mfma_f32_16x16x32_bf16(af[i], bf[j], acc[i][j], 0, 0, 0);
    __builtin_amdgcn_s_barrier();
  }

  const int lrr = (lane >> 4) * 4;
  #pragma unroll
  for (int i = 0; i < 4; i++) {
    #pragma unroll
    for (int r = 0; r < 4; r++) {
      int m = m0 + wm + i * 16 + lrr + r;
      float wv = sgate[m];
      size_t row = (size_t)m * N;
      #pragma unroll
      for (int j = 0; j < 2; j++) {
        int c = n0 + wn + j * 16 + lr;
        atomicAdd(&out[row + c], wv * acc[i][j][r]);
      }
    }
  }
}

// ---------------- merged gate/up + distributed aux epilogue -----------------
// gu_m block ranges: [0,704) shared gate/up (XCD rect 8m x 11n, m-inner);
// [704,1728) routed (e = rid&7 keeps expert->XCD affinity; 16 mb/expert).
// EVERY block then runs a grid-strided slice of {dn-weight cvt, out-zero}
// as an epilogue (R15 lesson: tail-appended aux blocks dispatch in-order and
// serialize; per-block epilogue slices overlap the staggered GEMM phase, and
// the ~512 no-op routed blocks become immediate concurrent BW workers).
#define GU_SH_BLKS 704
#define GU_RT_BLKS 1024
#define GU_TOT (GU_SH_BLKS + GU_RT_BLKS)

__global__ __launch_bounds__(256, 2) void gemm_gu_m(
    const ushort* __restrict__ Xb,
    const ushort* __restrict__ sgB, const ushort* __restrict__ suB,
    const ushort* __restrict__ wgB, const ushort* __restrict__ wuB,
    ushort* __restrict__ Sbuf, ushort* __restrict__ Hbuf,
    const int* __restrict__ tokmap, const int* __restrict__ cnts,
    const int* __restrict__ offs,
    const float* __restrict__ wd, ushort* __restrict__ wdB,
    const float* __restrict__ swd, ushort* __restrict__ sdB,
    float* __restrict__ out) {
  __shared__ ushort lds[24576];   // 48KB, GEMM paths only
  const int id = blockIdx.x;
  if (id < GU_SH_BLKS) {
    int x = id & 7, k = id >> 3;
    int mb = (x & 3) * 8 + (k & 7);
    int nb = (x >> 2) * 11 + (k >> 3);
    gu_core<false>(Xb, sgB, suB, Sbuf, nullptr, TT, 0, mb, nb, SID, HD, lds);
  } else {
    int rid = id - GU_SH_BLKS;
    int e = rid & 7, k = rid >> 3;
    int mb = k >> 3, nb = k & 7;
    gu_core<true>(Xb, wgB + (size_t)e * ID * HD, wuB + (size_t)e * ID * HD,
                  Hbuf, tokmap, cnts[e], offs[e], mb, nb, ID, HD, lds);
  }

  // ---- epilogue: grid-strided dn-weight cvt + out-zero (for dn_m) ----
  {
    const int tid = threadIdx.x;
    const int base0 = (id * 256 + tid) * 4;
    const int stride = GU_TOT * 1024;
    const int n0 = NE * HD * ID;
    for (int i = base0; i < n0; i += stride) {
      f32x4v v = *(const f32x4v*)(wd + i);
      u16x4 o;
      o.x = f2bf(v.x); o.y = f2bf(v.y); o.z = f2bf(v.z); o.w = f2bf(v.w);
      *(u16x4*)(wdB + i) = o;
    }
    const int n1 = HD * SID;
    for (int i = base0; i < n1; i += stride) {
      f32x4v v = *(const f32x4v*)(swd + i);
      u16x4 o;
      o.x = f2bf(v.x); o.y = f2bf(v.y); o.z = f2bf(v.z); o.w = f2bf(v.w);
      *(u16x4*)(sdB + i) = o;
    }
    const int n2 = TT * HD;
    for (int i = base0; i < n2; i += stride)
      *(f32x4*)&out[i] = f32x4{0.f, 0.f, 0.f, 0.f};
  }
}

// dn_m: [0,512) shared down (atomic out += sgate*val); [512,1536) routed
// down (atomic out += w*val; 16 mb/expert). Atomics commute (G16-safe).
#define DN_SH_BLKS 512
#define DN_RT_BLKS 1024
__global__ __launch_bounds__(256, 2) void gemm_dn_m(
    const ushort* __restrict__ Sbuf, const ushort* __restrict__ sdB,
    const ushort* __restrict__ Hbuf, const ushort* __restrict__ wdB,
    float* __restrict__ out, const float* __restrict__ sgate,
    const int* __restrict__ tokmap, const float* __restrict__ wmap,
    const int* __restrict__ cnts, const int* __restrict__ offs) {
  __shared__ ushort lds[16384];   // 32KB shared by both paths
  int id = blockIdx.x;
  if (id < DN_SH_BLKS) {
    int x = id & 7, kk = id >> 3;
    int mb = x * 4 + (kk & 3);
    int nb = kk >> 2;
    dn_s_core(Sbuf, sdB, out, sgate, mb, nb, HD, SID, lds);
  } else {
    int rid = id - DN_SH_BLKS;
    int e = rid & 7, k = rid >> 3;
    int mb = k >> 3, nb = k & 7;
    dn_r_core(Hbuf, wdB + (size_t)e * HD * ID, out, tokmap, wmap,
              cnts[e], offs[e], mb, nb, HD, ID, lds);
  }
}

// ---------------------------------------------------------------------------
extern "C" void kernel_launch(void* const* d_in, const int* in_sizes, int n_in,
                              void* d_out, int out_size, void* d_ws, size_t ws_size,
                              hipStream_t stream) {
  const float* hs  = (const float*)d_in[0];
  const float* gw  = (const float*)d_in[1];
  const float* wg  = (const float*)d_in[2];
  const float* wu  = (const float*)d_in[3];
  const float* wd  = (const float*)d_in[4];
  const float* swg = (const float*)d_in[5];
  const float* swu = (const float*)d_in[6];
  const float* swd = (const float*)d_in[7];
  const float* sgw = (const float*)d_in[8];
  float* out = (float*)d_out;

  uint8_t* base = (uint8_t*)d_ws;
  size_t off = 0;
  auto give = [&](size_t b) -> void* {
    void* p = base + off;
    off += (b + 255) & ~(size_t)255;
    return p;
  };
  ushort* Xb   = (ushort*)give((size_t)TT * HD * 2);
  ushort* wgB  = (ushort*)give((size_t)NE * ID * HD * 2);
  ushort* wuB  = (ushort*)give((size_t)NE * ID * HD * 2);
  ushort* wdB  = (ushort*)give((size_t)NE * HD * ID * 2);
  ushort* sgB  = (ushort*)give((size_t)SID * HD * 2);
  ushort* suB  = (ushort*)give((size_t)SID * HD * 2);
  ushort* sdB  = (ushort*)give((size_t)HD * SID * 2);
  ushort* Sbuf = (ushort*)give((size_t)TT * SID * 2);
  ushort* Hbuf = (ushort*)give((size_t)2 * TT * ID * 2);
  float* sgate = (float*)give(TT * 4);
  int* topki   = (int*)give(TT * 2 * 4);
  float* topkw = (float*)give(TT * 2 * 4);
  int* tokmap  = (int*)give(2 * TT * 4);
  float* wmap  = (float*)give(2 * TT * 4);
  int* cnt     = (int*)give(256);
  int* offs    = (int*)give(256);

  // 1. prep: router ∥ gu-path weight cvt
  PrepArgs pa;
  pa.src[0] = wg;  pa.dst[0] = wgB; pa.n[0] = NE * ID * HD;
  pa.src[1] = wu;  pa.dst[1] = wuB; pa.n[1] = NE * ID * HD;
  pa.src[2] = swg; pa.dst[2] = sgB; pa.n[2] = SID * HD;
  pa.src[3] = swu; pa.dst[3] = suB; pa.n[3] = SID * HD;
  pa.X = hs; pa.gw = gw; pa.sgw = sgw; pa.Xb = Xb;
  pa.topki = topki; pa.topkw = topkw; pa.sgate = sgate;
  prep_k<<<RTR_BLKS + CVT_BLKS, 256, 0, stream>>>(pa);

  // 2. binning (ballot-based, no atomics)
  binning_k<<<1, 1024, 0, stream>>>(topki, topkw, cnt, offs, tokmap, wmap);

  // 3. merged gate/up; every block also does an aux epilogue slice
  gemm_gu_m<<<GU_TOT, 256, 0, stream>>>(
      Xb, sgB, suB, wgB, wuB, Sbuf, Hbuf, tokmap, cnt, offs,
      wd, wdB, swd, sdB, out);

  // 4. merged down-proj: shared + routed, atomically into zeroed out
  gemm_dn_m<<<DN_SH_BLKS + DN_RT_BLKS, 256, 0, stream>>>(
      Sbuf, sdB, Hbuf, wdB, out, sgate, tokmap, wmap, cnt, offs);
}

// Round 17
// 231.420 us; speedup vs baseline: 1.0316x; 1.0316x over previous
//
#include <hip/hip_runtime.h>
#include <stdint.h>

#define TT  4096   // tokens = B*S
#define HD  1024   // hidden
#define NE  8      // experts
#define ID  1024   // expert intermediate
#define SID 2816   // shared intermediate

typedef short s16x8 __attribute__((ext_vector_type(8)));
typedef float f32x4 __attribute__((ext_vector_type(4)));
typedef float f32x4v __attribute__((ext_vector_type(4)));
typedef unsigned short u16x4 __attribute__((ext_vector_type(4)));

__device__ __forceinline__ ushort f2bf(float f) {
  uint32_t u = __float_as_uint(f);
  u += 0x7FFFu + ((u >> 16) & 1u);   // RNE
  return (ushort)(u >> 16);
}

__device__ __forceinline__ void gll16(const ushort* g, ushort* l) {
  __builtin_amdgcn_global_load_lds(
      (const __attribute__((address_space(1))) void*)g,
      (__attribute__((address_space(3))) void*)l, 16, 0, 0);
}

// ---------------- prep: router ∥ out-zero ∥ weight-cvt in ONE launch -------
// R14-proven optimum (232us). R15/R16 showed moving the dn-cvt/zero into
// gu_m COSTS 15-25us: at 2 blocks/CU a BW epilogue holds the CU slot the
// next GEMM block needs. Independent flat work merges fine (router ∥ cvt);
// BW work under a low-occupancy GEMM does not.
#define RTR_BLKS 256
#define ZERO_BLKS 128
#define CVT_BLKS 2048

struct PrepArgs {
  const float* src[6];
  ushort* dst[6];
  int n[6];
  const float* X;
  const float* gw;
  const float* sgw;
  ushort* Xb;
  int* topki;
  float* topkw;
  float* sgate;
  float* out;
};

__global__ __launch_bounds__(256) void prep_k(PrepArgs a) {
  __shared__ float gwL[(NE + 1) * HD];   // router blocks only (36KB)
  const int id = blockIdx.x;
  const int tid = threadIdx.x;

  if (id < RTR_BLKS) {
    // ---- router (pure; also emits Xb = bf16(X)) ----
    #pragma unroll
    for (int i = 0; i < NE * HD / 1024; i++) {
      int idx = i * 1024 + tid * 4;
      *(f32x4*)&gwL[idx] = *(const f32x4*)&a.gw[idx];
    }
    {
      int idx = tid * 4;
      if (idx < HD) *(f32x4*)&gwL[NE * HD + idx] = *(const f32x4*)&a.sgw[idx];
    }
    __syncthreads();

    const int wave = tid >> 6, lane = tid & 63;
    #pragma unroll
    for (int tt = 0; tt < 4; tt++) {
      const int t = id * 16 + wave * 4 + tt;
      const float* x = a.X + (size_t)t * HD;
      float acc[NE + 1];
      #pragma unroll
      for (int e = 0; e <= NE; e++) acc[e] = 0.f;
      #pragma unroll
      for (int p = 0; p < HD / 256; p++) {
        const int k = p * 256 + lane * 4;
        f32x4 xv = *(const f32x4*)&x[k];
        u16x4 xb;
        xb.x = f2bf(xv.x); xb.y = f2bf(xv.y); xb.z = f2bf(xv.z); xb.w = f2bf(xv.w);
        *(u16x4*)&a.Xb[(size_t)t * HD + k] = xb;
        #pragma unroll
        for (int e = 0; e < NE; e++) {
          f32x4 g = *(const f32x4*)&gwL[e * HD + k];
          acc[e] += xv.x * g.x + xv.y * g.y + xv.z * g.z + xv.w * g.w;
        }
        f32x4 s = *(const f32x4*)&gwL[NE * HD + k];
        acc[NE] += xv.x * s.x + xv.y * s.y + xv.z * s.z + xv.w * s.w;
      }
      #pragma unroll
      for (int off = 32; off > 0; off >>= 1)
        #pragma unroll
        for (int e = 0; e <= NE; e++)
          acc[e] += __shfl_xor(acc[e], off, 64);
      if (lane == 0) {
        float m = acc[0];
        #pragma unroll
        for (int e = 1; e < NE; e++) m = fmaxf(m, acc[e]);
        float p[NE];
        #pragma unroll
        for (int e = 0; e < NE; e++) p[e] = __expf(acc[e] - m);
        int i1 = 0;
        #pragma unroll
        for (int e = 1; e < NE; e++) if (p[e] > p[i1]) i1 = e;
        int i2 = (i1 == 0) ? 1 : 0;
        #pragma unroll
        for (int e = 0; e < NE; e++) if (e != i1 && p[e] > p[i2]) i2 = e;
        float inv = 1.f / (p[i1] + p[i2]);
        a.topki[2 * t] = i1; a.topki[2 * t + 1] = i2;
        a.topkw[2 * t] = p[i1] * inv; a.topkw[2 * t + 1] = p[i2] * inv;
        a.sgate[t] = 1.f / (1.f + __expf(-acc[NE]));
      }
    }
  } else if (id < RTR_BLKS + ZERO_BLKS) {
    // ---- zero out (dn_m accumulates atomically into it) ----
    const int zid = id - RTR_BLKS;
    const int total = TT * HD;
    for (int i = (zid * 256 + tid) * 4; i < total; i += ZERO_BLKS * 1024)
      *(f32x4*)&a.out[i] = f32x4{0.f, 0.f, 0.f, 0.f};
  } else {
    // ---- weight cvt, grid-stride, lane-consecutive 16B (coalesced) ----
    const int cid = id - RTR_BLKS - ZERO_BLKS;
    #pragma unroll
    for (int t = 0; t < 6; t++) {
      const float* s = a.src[t];
      ushort* d = a.dst[t];
      const int n = a.n[t];
      for (int i = (cid * 256 + tid) * 4; i < n; i += CVT_BLKS * 1024) {
        f32x4v v = *(const f32x4v*)(s + i);
        u16x4 o;
        o.x = f2bf(v.x); o.y = f2bf(v.y); o.z = f2bf(v.z); o.w = f2bf(v.w);
        *(u16x4*)(d + i) = o;
      }
    }
  }
}

// ---------------- binning: ballot-based, zero atomics ----------------------
__global__ __launch_bounds__(1024) void binning_k(
    const int* __restrict__ topki, const float* __restrict__ topkw,
    int* __restrict__ cnt, int* __restrict__ offs,
    int* __restrict__ tokmap, float* __restrict__ wmap) {
  __shared__ int wc[16][NE];
  __shared__ int wbase[16][NE];
  const int tid = threadIdx.x;
  const int wave = tid >> 6, lane = tid & 63;
  const uint64_t ltmask = ((uint64_t)1 << lane) - 1;

  int wcnt[NE];
  #pragma unroll
  for (int e = 0; e < NE; e++) wcnt[e] = 0;
  int mye[8], myoff[8];
  #pragma unroll
  for (int it = 0; it < 8; it++) {
    int s = wave * 512 + it * 64 + lane;
    int e = topki[s];
    mye[it] = e;
    myoff[it] = 0;
    #pragma unroll
    for (int ee = 0; ee < NE; ee++) {
      uint64_t m = __ballot(e == ee);
      if (e == ee) myoff[it] = wcnt[ee] + __popcll(m & ltmask);
      wcnt[ee] += __popcll(m);
    }
  }
  if (lane == 0) {
    #pragma unroll
    for (int e = 0; e < NE; e++) wc[wave][e] = wcnt[e];
  }
  __syncthreads();
  if (tid == 0) {
    int o = 0;
    for (int e = 0; e < NE; e++) {
      offs[e] = o;
      int tot = 0;
      for (int w = 0; w < 16; w++) { wbase[w][e] = o + tot; tot += wc[w][e]; }
      cnt[e] = tot;
      o += tot;
    }
  }
  __syncthreads();
  #pragma unroll
  for (int it = 0; it < 8; it++) {
    int s = wave * 512 + it * 64 + lane;
    int e = mye[it];
    int pos = wbase[wave][e] + myoff[it];
    tokmap[pos] = s >> 1;
    wmap[pos] = topkw[s];
  }
}

// ---------------- GEMM cores (128-tile, 2-buf, swizzled, LDS passed in) ----
// LDS rows 64B (32 bf16). Write side pre-swizzles GLOBAL 16B chunk
// ((l&3)^((l>>3)&3)); LDS dest linear (global_load_lds rule); read side
// applies same involution -> 0 bank conflicts (verified R3/R9/R10).
constexpr int BM = 128, BN = 128, BK = 32;

template <bool GATHER>
__device__ __forceinline__ void gu_core(
    const ushort* __restrict__ A, const ushort* __restrict__ Wg,
    const ushort* __restrict__ Wu, ushort* __restrict__ Hout,
    const int* __restrict__ tokmap, int cnt, int seg,
    int mb, int nb, int N, int K, ushort* lds) {
  const int m0 = mb * BM;
  if (m0 >= cnt) return;
  const int n0 = nb * BN;

  ushort* lA  = lds;           // 2 x 4096
  ushort* lBg = lds + 8192;    // 2 x 4096
  ushort* lBu = lds + 16384;   // 2 x 4096

  const int tid = threadIdx.x;
  const int wave = tid >> 6, lane = tid & 63;
  const int wm = (wave >> 1) * 64, wn = (wave & 1) * 64;

  const int ar0 = wave * 32 + (lane >> 2);
  const int ar1 = ar0 + 16;
  const int kc = ((lane & 3) ^ ((lane >> 3) & 3)) * 8;

  const ushort *a0p, *a1p;
  if (GATHER) {
    int m_ = m0 + ar0;
    int tk0 = (m_ < cnt) ? tokmap[seg + m_] : 0;
    m_ = m0 + ar1;
    int tk1 = (m_ < cnt) ? tokmap[seg + m_] : 0;
    a0p = A + (size_t)tk0 * K + kc;
    a1p = A + (size_t)tk1 * K + kc;
  } else {
    a0p = A + (size_t)(m0 + ar0) * K + kc;
    a1p = A + (size_t)(m0 + ar1) * K + kc;
  }
  const ushort* bg0 = Wg + (size_t)(n0 + ar0) * K + kc;
  const ushort* bg1 = Wg + (size_t)(n0 + ar1) * K + kc;
  const ushort* bu0 = Wu + (size_t)(n0 + ar0) * K + kc;
  const ushort* bu1 = Wu + (size_t)(n0 + ar1) * K + kc;

  f32x4 accG[4][4], accU[4][4];
  #pragma unroll
  for (int i = 0; i < 4; i++)
    #pragma unroll
    for (int j = 0; j < 4; j++) {
      accG[i][j] = f32x4{0.f, 0.f, 0.f, 0.f};
      accU[i][j] = f32x4{0.f, 0.f, 0.f, 0.f};
    }

  const int lr = lane & 15;
  const int lk = (((lane >> 4) ^ ((lr >> 1) & 3))) * 8;
  const int w32 = wave * 32;

  auto stage = [&](int b, int k0) {
    gll16(a0p + k0, &lA[b * 4096 + w32 * BK]);
    gll16(a1p + k0, &lA[b * 4096 + (w32 + 16) * BK]);
    gll16(bg0 + k0, &lBg[b * 4096 + w32 * BK]);
    gll16(bg1 + k0, &lBg[b * 4096 + (w32 + 16) * BK]);
    gll16(bu0 + k0, &lBu[b * 4096 + w32 * BK]);
    gll16(bu1 + k0, &lBu[b * 4096 + (w32 + 16) * BK]);
  };

  const int nt = K / BK;
  stage(0, 0);
  for (int t = 0; t < nt; t++) {
    const int cur = t & 1;
    if (t + 1 < nt) {
      stage(cur ^ 1, (t + 1) * BK);
      asm volatile("s_waitcnt vmcnt(6)" ::: "memory");
    } else {
      asm volatile("s_waitcnt vmcnt(0)" ::: "memory");
    }
    __builtin_amdgcn_s_barrier();

    s16x8 af[4], bgf[4], buf_[4];
    #pragma unroll
    for (int i = 0; i < 4; i++) {
      af[i]   = *(const s16x8*)&lA [cur * 4096 + (wm + i * 16 + lr) * BK + lk];
      bgf[i]  = *(const s16x8*)&lBg[cur * 4096 + (wn + i * 16 + lr) * BK + lk];
      buf_[i] = *(const s16x8*)&lBu[cur * 4096 + (wn + i * 16 + lr) * BK + lk];
    }
    #pragma unroll
    for (int i = 0; i < 4; i++)
      #pragma unroll
      for (int j = 0; j < 4; j++) {
        accG[i][j] = __builtin_amdgcn_mfma_f32_16x16x32_bf16(af[i], bgf[j], accG[i][j], 0, 0, 0);
        accU[i][j] = __builtin_amdgcn_mfma_f32_16x16x32_bf16(af[i], buf_[j], accU[i][j], 0, 0, 0);
      }
    __builtin_amdgcn_s_barrier();
  }

  const int lrr = (lane >> 4) * 4;
  #pragma unroll
  for (int i = 0; i < 4; i++) {
    #pragma unroll
    for (int r = 0; r < 4; r++) {
      int m = wm + i * 16 + lrr + r;
      if (m0 + m < cnt) {
        size_t row = (size_t)(seg + m0 + m) * N;
        #pragma unroll
        for (int j = 0; j < 4; j++) {
          int c = n0 + wn + j * 16 + lr;
          float g = accG[i][j][r];
          float u = accU[i][j][r];
          float s = g / (1.f + __expf(-g));   // silu
          Hout[row + c] = f2bf(s * u);
        }
      }
    }
  }
}

// routed down-proj 128x128 core: atomicAdd(w * val) direct to out
__device__ __forceinline__ void dn_r_core(
    const ushort* __restrict__ A, const ushort* __restrict__ W,
    float* __restrict__ out, const int* __restrict__ tokmap,
    const float* __restrict__ wmap, int cnt, int seg,
    int mb, int nb, int N, int K, ushort* lds) {
  const int m0 = mb * BM;
  if (m0 >= cnt) return;
  const int n0 = nb * BN;

  ushort* lA = lds;          // 2 x 4096
  ushort* lB = lds + 8192;   // 2 x 4096

  const int tid = threadIdx.x;
  const int wave = tid >> 6, lane = tid & 63;
  const int wm = (wave >> 1) * 64, wn = (wave & 1) * 64;

  const int ar0 = wave * 32 + (lane >> 2);
  const int ar1 = ar0 + 16;
  const int kc = ((lane & 3) ^ ((lane >> 3) & 3)) * 8;

  int r0 = m0 + ar0; if (r0 > cnt - 1) r0 = cnt - 1;
  int r1 = m0 + ar1; if (r1 > cnt - 1) r1 = cnt - 1;
  const ushort* a0p = A + (size_t)(seg + r0) * K + kc;
  const ushort* a1p = A + (size_t)(seg + r1) * K + kc;
  const ushort* b0 = W + (size_t)(n0 + ar0) * K + kc;
  const ushort* b1 = W + (size_t)(n0 + ar1) * K + kc;

  f32x4 acc[4][4];
  #pragma unroll
  for (int i = 0; i < 4; i++)
    #pragma unroll
    for (int j = 0; j < 4; j++) acc[i][j] = f32x4{0.f, 0.f, 0.f, 0.f};

  const int lr = lane & 15;
  const int lk = (((lane >> 4) ^ ((lr >> 1) & 3))) * 8;
  const int w32 = wave * 32;

  auto stage = [&](int b, int k0) {
    gll16(a0p + k0, &lA[b * 4096 + w32 * BK]);
    gll16(a1p + k0, &lA[b * 4096 + (w32 + 16) * BK]);
    gll16(b0 + k0, &lB[b * 4096 + w32 * BK]);
    gll16(b1 + k0, &lB[b * 4096 + (w32 + 16) * BK]);
  };

  const int nt = K / BK;
  stage(0, 0);
  for (int t = 0; t < nt; t++) {
    const int cur = t & 1;
    if (t + 1 < nt) {
      stage(cur ^ 1, (t + 1) * BK);
      asm volatile("s_waitcnt vmcnt(4)" ::: "memory");
    } else {
      asm volatile("s_waitcnt vmcnt(0)" ::: "memory");
    }
    __builtin_amdgcn_s_barrier();

    s16x8 af[4], bf[4];
    #pragma unroll
    for (int i = 0; i < 4; i++) {
      af[i] = *(const s16x8*)&lA[cur * 4096 + (wm + i * 16 + lr) * BK + lk];
      bf[i] = *(const s16x8*)&lB[cur * 4096 + (wn + i * 16 + lr) * BK + lk];
    }
    #pragma unroll
    for (int i = 0; i < 4; i++)
      #pragma unroll
      for (int j = 0; j < 4; j++)
        acc[i][j] = __builtin_amdgcn_mfma_f32_16x16x32_bf16(af[i], bf[j], acc[i][j], 0, 0, 0);
    __builtin_amdgcn_s_barrier();
  }

  const int lrr = (lane >> 4) * 4;
  #pragma unroll
  for (int i = 0; i < 4; i++) {
    #pragma unroll
    for (int r = 0; r < 4; r++) {
      int m = wm + i * 16 + lrr + r;
      if (m0 + m < cnt) {
        int slot = seg + m0 + m;
        int t = tokmap[slot];
        float wv = wmap[slot];
        size_t row = (size_t)t * N;
        #pragma unroll
        for (int j = 0; j < 4; j++) {
          int c = n0 + wn + j * 16 + lr;
          atomicAdd(&out[row + c], wv * acc[i][j][r]);
        }
      }
    }
  }
}

// shared down-proj 128x64 core: atomicAdd(sgate * val) to out
__device__ __forceinline__ void dn_s_core(
    const ushort* __restrict__ A, const ushort* __restrict__ W,
    float* __restrict__ out, const float* __restrict__ sgate,
    int mb, int nb, int N, int K, ushort* lds) {
  const int m0 = mb * 128, n0 = nb * 64;

  ushort* lA = lds;          // 2 x 4096
  ushort* lB = lds + 8192;   // 2 x 2048

  const int tid = threadIdx.x;
  const int wave = tid >> 6, lane = tid & 63;
  const int wm = (wave >> 1) * 64, wn = (wave & 1) * 32;

  const int ar0 = wave * 32 + (lane >> 2);
  const int ar1 = ar0 + 16;
  const int br  = wave * 16 + (lane >> 2);
  const int kc = ((lane & 3) ^ ((lane >> 3) & 3)) * 8;

  const ushort* a0p = A + (size_t)(m0 + ar0) * K + kc;
  const ushort* a1p = A + (size_t)(m0 + ar1) * K + kc;
  const ushort* bp  = W + (size_t)(n0 + br) * K + kc;

  f32x4 acc[4][2];
  #pragma unroll
  for (int i = 0; i < 4; i++)
    #pragma unroll
    for (int j = 0; j < 2; j++) acc[i][j] = f32x4{0.f, 0.f, 0.f, 0.f};

  const int lr = lane & 15;
  const int lk = (((lane >> 4) ^ ((lr >> 1) & 3))) * 8;
  const int w32 = wave * 32;

  auto stage = [&](int b, int k0) {
    gll16(a0p + k0, &lA[b * 4096 + w32 * 32]);
    gll16(a1p + k0, &lA[b * 4096 + (w32 + 16) * 32]);
    gll16(bp + k0, &lB[b * 2048 + wave * 512]);
  };

  const int nt = K / 32;
  stage(0, 0);
  for (int t = 0; t < nt; t++) {
    const int cur = t & 1;
    if (t + 1 < nt) {
      stage(cur ^ 1, (t + 1) * 32);
      asm volatile("s_waitcnt vmcnt(3)" ::: "memory");
    } else {
      asm volatile("s_waitcnt vmcnt(0)" ::: "memory");
    }
    __builtin_amdgcn_s_barrier();

    s16x8 af[4], bf[2];
    #pragma unroll
    for (int i = 0; i < 4; i++)
      af[i] = *(const s16x8*)&lA[cur * 4096 + (wm + i * 16 + lr) * 32 + lk];
    #pragma unroll
    for (int j = 0; j < 2; j++)
      bf[j] = *(const s16x8*)&lB[cur * 2048 + (wn + j * 16 + lr) * 32 + lk];
    #pragma unroll
    for (int i = 0; i < 4; i++)
      #pragma unroll
      for (int j = 0; j < 2; j++)
        acc[i][j] = __builtin_amdgcn_mfma_f32_16x16x32_bf16(af[i], bf[j], acc[i][j], 0, 0, 0);
    __builtin_amdgcn_s_barrier();
  }

  const int lrr = (lane >> 4) * 4;
  #pragma unroll
  for (int i = 0; i < 4; i++) {
    #pragma unroll
    for (int r = 0; r < 4; r++) {
      int m = m0 + wm + i * 16 + lrr + r;
      float wv = sgate[m];
      size_t row = (size_t)m * N;
      #pragma unroll
      for (int j = 0; j < 2; j++) {
        int c = n0 + wn + j * 16 + lr;
        atomicAdd(&out[row + c], wv * acc[i][j][r]);
      }
    }
  }
}

// ---------------- merged kernels --------------------------------------------
// gu_m: id<704 -> shared gate/up (XCD rect: resident 2MB A + 0.5MB B < L2);
// id>=704 -> routed, e = rid&7 so id%8 == e keeps expert->XCD affinity.
#define GU_SH_BLKS 704
#define GU_RT_BLKS 1024
__global__ __launch_bounds__(256, 2) void gemm_gu_m(
    const ushort* __restrict__ Xb,
    const ushort* __restrict__ sgB, const ushort* __restrict__ suB,
    const ushort* __restrict__ wgB, const ushort* __restrict__ wuB,
    ushort* __restrict__ Sbuf, ushort* __restrict__ Hbuf,
    const int* __restrict__ tokmap, const int* __restrict__ cnts,
    const int* __restrict__ offs) {
  __shared__ ushort lds[24576];   // 48KB shared by both paths
  int id = blockIdx.x;
  if (id < GU_SH_BLKS) {
    int x = id & 7, k = id >> 3;
    int mb = (x & 3) * 8 + (k & 7);
    int nb = (x >> 2) * 11 + (k >> 3);
    gu_core<false>(Xb, sgB, suB, Sbuf, nullptr, TT, 0, mb, nb, SID, HD, lds);
  } else {
    int rid = id - GU_SH_BLKS;
    int e = rid & 7, k = rid >> 3;
    int mb = k >> 3, nb = k & 7;
    gu_core<true>(Xb, wgB + (size_t)e * ID * HD, wuB + (size_t)e * ID * HD,
                  Hbuf, tokmap, cnts[e], offs[e], mb, nb, ID, HD, lds);
  }
}

// dn_m: id<512 -> shared down (atomic out += sgate*val); else routed down
// (atomic out += w*val). Out zeroed by prep_k; atomics commute (G16-safe).
#define DN_SH_BLKS 512
#define DN_RT_BLKS 1024
__global__ __launch_bounds__(256, 2) void gemm_dn_m(
    const ushort* __restrict__ Sbuf, const ushort* __restrict__ sdB,
    const ushort* __restrict__ Hbuf, const ushort* __restrict__ wdB,
    float* __restrict__ out, const float* __restrict__ sgate,
    const int* __restrict__ tokmap, const float* __restrict__ wmap,
    const int* __restrict__ cnts, const int* __restrict__ offs) {
  __shared__ ushort lds[16384];   // 32KB shared by both paths
  int id = blockIdx.x;
  if (id < DN_SH_BLKS) {
    int x = id & 7, kk = id >> 3;
    int mb = x * 4 + (kk & 3);
    int nb = kk >> 2;
    dn_s_core(Sbuf, sdB, out, sgate, mb, nb, HD, SID, lds);
  } else {
    int rid = id - DN_SH_BLKS;
    int e = rid & 7, k = rid >> 3;
    int mb = k >> 3, nb = k & 7;
    dn_r_core(Hbuf, wdB + (size_t)e * HD * ID, out, tokmap, wmap,
              cnts[e], offs[e], mb, nb, HD, ID, lds);
  }
}

// ---------------------------------------------------------------------------
extern "C" void kernel_launch(void* const* d_in, const int* in_sizes, int n_in,
                              void* d_out, int out_size, void* d_ws, size_t ws_size,
                              hipStream_t stream) {
  const float* hs  = (const float*)d_in[0];
  const float* gw  = (const float*)d_in[1];
  const float* wg  = (const float*)d_in[2];
  const float* wu  = (const float*)d_in[3];
  const float* wd  = (const float*)d_in[4];
  const float* swg = (const float*)d_in[5];
  const float* swu = (const float*)d_in[6];
  const float* swd = (const float*)d_in[7];
  const float* sgw = (const float*)d_in[8];
  float* out = (float*)d_out;

  uint8_t* base = (uint8_t*)d_ws;
  size_t off = 0;
  auto give = [&](size_t b) -> void* {
    void* p = base + off;
    off += (b + 255) & ~(size_t)255;
    return p;
  };
  ushort* Xb   = (ushort*)give((size_t)TT * HD * 2);
  ushort* wgB  = (ushort*)give((size_t)NE * ID * HD * 2);
  ushort* wuB  = (ushort*)give((size_t)NE * ID * HD * 2);
  ushort* wdB  = (ushort*)give((size_t)NE * HD * ID * 2);
  ushort* sgB  = (ushort*)give((size_t)SID * HD * 2);
  ushort* suB  = (ushort*)give((size_t)SID * HD * 2);
  ushort* sdB  = (ushort*)give((size_t)HD * SID * 2);
  ushort* Sbuf = (ushort*)give((size_t)TT * SID * 2);
  ushort* Hbuf = (ushort*)give((size_t)2 * TT * ID * 2);
  float* sgate = (float*)give(TT * 4);
  int* topki   = (int*)give(TT * 2 * 4);
  float* topkw = (float*)give(TT * 2 * 4);
  int* tokmap  = (int*)give(2 * TT * 4);
  float* wmap  = (float*)give(2 * TT * 4);
  int* cnt     = (int*)give(256);
  int* offs    = (int*)give(256);

  // 1. prep: router ∥ out-zero ∥ weight-cvt in one launch
  PrepArgs pa;
  pa.src[0] = wg;  pa.dst[0] = wgB; pa.n[0] = NE * ID * HD;
  pa.src[1] = wu;  pa.dst[1] = wuB; pa.n[1] = NE * ID * HD;
  pa.src[2] = wd;  pa.dst[2] = wdB; pa.n[2] = NE * HD * ID;
  pa.src[3] = swg; pa.dst[3] = sgB; pa.n[3] = SID * HD;
  pa.src[4] = swu; pa.dst[4] = suB; pa.n[4] = SID * HD;
  pa.src[5] = swd; pa.dst[5] = sdB; pa.n[5] = HD * SID;
  pa.X = hs; pa.gw = gw; pa.sgw = sgw; pa.Xb = Xb;
  pa.topki = topki; pa.topkw = topkw; pa.sgate = sgate; pa.out = out;
  prep_k<<<RTR_BLKS + ZERO_BLKS + CVT_BLKS, 256, 0, stream>>>(pa);

  // 2. binning (ballot-based, no atomics)
  binning_k<<<1, 1024, 0, stream>>>(topki, topkw, cnt, offs, tokmap, wmap);

  // 3. merged gate/up: shared (704 blocks) + routed (8 x 16mb x 8nb)
  gemm_gu_m<<<GU_SH_BLKS + GU_RT_BLKS, 256, 0, stream>>>(
      Xb, sgB, suB, wgB, wuB, Sbuf, Hbuf, tokmap, cnt, offs);

  // 4. merged down-proj: shared + routed, atomically into zeroed out
  gemm_dn_m<<<DN_SH_BLKS + DN_RT_BLKS, 256, 0, stream>>>(
      Sbuf, sdB, Hbuf, wdB, out, sgate, tokmap, wmap, cnt, offs);
}